// Round 3
// baseline (236.702 us; speedup 1.0000x reference)
//
#include <hip/hip_runtime.h>
#include <hip/hip_bf16.h>

#define L 512
#define CS 256
#define CZ 128
#define LN_EPS 1e-5f

typedef _Float16 f16_t;
typedef f16_t f16x8 __attribute__((ext_vector_type(8)));
typedef float f32x4 __attribute__((ext_vector_type(4)));
typedef float f32x16 __attribute__((ext_vector_type(16)));

// ---- Kernel S: embed + LN -> s, u_f16; zrow = u@W1 + b, zcol = u@W2 -------
__global__ __launch_bounds__(256) void k_setup(
    const int* __restrict__ seq, const int* __restrict__ cid,
    const int* __restrict__ ridx,
    const float* __restrict__ Eaa, const float* __restrict__ Epos,
    const float* __restrict__ Ech, const float* __restrict__ lnw,
    const float* __restrict__ lnb, const float* __restrict__ Wp,
    const float* __restrict__ bp,
    float* __restrict__ s_out, f16_t* __restrict__ u_f16,
    float* __restrict__ zrow, float* __restrict__ zcol)
{
    __shared__ float su[CS];
    __shared__ float red[8];
    const int i = blockIdx.x;
    const int c = threadIdx.x;
    const int sq = seq[i], ri = ridx[i], ci = cid[i];
    const float v = Eaa[sq * CS + c] + Epos[ri * CS + c] + Ech[ci * CS + c];
    s_out[i * CS + c] = v;

    float s1 = v, s2 = v * v;
    #pragma unroll
    for (int o = 32; o > 0; o >>= 1) {
        s1 += __shfl_down(s1, o, 64);
        s2 += __shfl_down(s2, o, 64);
    }
    const int wv = c >> 6, lane = c & 63;
    if (lane == 0) { red[wv * 2] = s1; red[wv * 2 + 1] = s2; }
    __syncthreads();
    const float S  = red[0] + red[2] + red[4] + red[6];
    const float SS = red[1] + red[3] + red[5] + red[7];
    const float mu  = S * (1.0f / CS);
    const float var = SS * (1.0f / CS) - mu * mu;
    const float rs  = rsqrtf(var + LN_EPS);
    const float u   = (v - mu) * rs * lnw[c] + lnb[c];
    u_f16[i * CS + c] = (f16_t)u;
    su[c] = u;
    __syncthreads();

    const int z = c & 127;
    const int half = c >> 7;  // 0 -> zrow(W1), 1 -> zcol(W2)
    const float* W = Wp + half * CS * CZ + z;
    // 4 interleaved partial sums break the serial FMA dependency chain.
    float a0 = 0, a1 = 0, a2 = 0, a3 = 0;
    #pragma unroll 8
    for (int cc = 0; cc < CS; cc += 4) {
        a0 += su[cc + 0] * W[(cc + 0) * CZ];
        a1 += su[cc + 1] * W[(cc + 1) * CZ];
        a2 += su[cc + 2] * W[(cc + 2) * CZ];
        a3 += su[cc + 3] * W[(cc + 3) * CZ];
    }
    const float acc = (a0 + a1) + (a2 + a3);
    if (half) zcol[i * CZ + z] = acc;
    else      zrow[i * CZ + z] = acc + bp[z];
}

// ---- Kernel T1: W3^T in f16 ------------------------------------------------
__global__ __launch_bounds__(128) void k_w3t(
    const float* __restrict__ Wp, f16_t* __restrict__ w3f)
{
    const int c = blockIdx.x;   // 0..255
    const int z = threadIdx.x;  // 0..127
    w3f[z * CS + c] = (f16_t)Wp[(2 * CS + c) * CZ + z];
}

// ---- Kernel T2: tab[cp*66+rp] = Ecp[cp] + Erp[rp] --------------------------
__global__ __launch_bounds__(128) void k_tab(
    const float* __restrict__ Ecp, const float* __restrict__ Erp,
    float* __restrict__ tab)
{
    const int b = blockIdx.x;   // 0..263
    const int z = threadIdx.x;  // 0..127
    tab[b * CZ + z] = Ecp[(b / 66) * CZ + z] + Erp[(b % 66) * CZ + z];
}

// ---- Kernel P: pair tensor --------------------------------------------------
// Grid (16,32): block = 16 i x 32 j x 128 z, 4 waves = 4 z-quarters.
// Wave: 32z x 32j via v_mfma_f32_32x32x16_f16, K=256 in 16 chunks.
//   A[ch] = W3T f16 frag (M=z, persistent, 64 VGPR)
//   UJ[ch] = u_f16[j] frag (persistent, 64 VGPR); B = ui*UJ via v_pk_mul_f16.
// C/D: col(lane&31)=j, row=(reg&3)+8*(reg>>2)+4*(lane>>5)=z -> per (i,j) row
// the wave's 4 f32x4 NT stores merge to exactly one 128B line. No LDS, no
// __syncthreads -> waves free-run against the HBM store floor (~21 us).
__global__ __launch_bounds__(256, 2) void k_pair(
    const f16_t* __restrict__ u_f16, const f16_t* __restrict__ w3f,
    const float* __restrict__ zrow, const float* __restrict__ zcol,
    const float* __restrict__ tab,
    const int* __restrict__ cid, const int* __restrict__ ridx,
    float* __restrict__ zout)
{
    const int lane = threadIdx.x & 63, wave = threadIdx.x >> 6;
    const int m32 = lane & 31, h = lane >> 5;
    const int z0 = wave * 32;
    const int i0 = blockIdx.y * 16;
    const int j  = blockIdx.x * 32 + m32;

    const f16x8* pw = (const f16x8*)w3f;   // [128][32] 8-elem units
    const f16x8* pu = (const f16x8*)u_f16; // [512][32]

    // Persistent fragments (loaded once, reused for 16 i's)
    f16x8 A[16], UJ[16];
    #pragma unroll
    for (int ch = 0; ch < 16; ++ch) {
        A[ch]  = pw[(z0 + m32) * 32 + ch * 2 + h];
        UJ[ch] = pu[j * 32 + ch * 2 + h];
    }

    const int cj = cid[j], rj = ridx[j];
    f32x4 ZC[4];
    #pragma unroll
    for (int r = 0; r < 4; ++r)
        ZC[r] = *(const f32x4*)&zcol[j * CZ + z0 + 8 * r + 4 * h];

    for (int rg = 0; rg < 16; ++rg) {
        const int i = i0 + rg;
        const f16x8* pui = pu + i * 32;

        f32x16 acc = {0, 0, 0, 0, 0, 0, 0, 0, 0, 0, 0, 0, 0, 0, 0, 0};
        #pragma unroll
        for (int ch = 0; ch < 16; ++ch) {
            f16x8 b = pui[ch * 2 + h] * UJ[ch];   // 4x v_pk_mul_f16
            acc = __builtin_amdgcn_mfma_f32_32x32x16_f16(A[ch], b, acc, 0, 0, 0);
        }

        const int ci = cid[i], riv = ridx[i];   // wave-uniform -> SGPR
        int d = riv - rj;
        d = d < -32 ? -32 : (d > 32 ? 32 : d);
        const int rp = (ci == cj) ? (d + 32) : 65;
        const int idx = (ci * 2 + cj) * 66 + rp;

        float* orow = zout + ((size_t)i * L + j) * CZ;
        #pragma unroll
        for (int r = 0; r < 4; ++r) {
            const int zq = z0 + 8 * r + 4 * h;
            f32x4 zr = *(const f32x4*)&zrow[i * CZ + zq];
            f32x4 tb = *(const f32x4*)&tab[idx * CZ + zq];
            f32x4 o;
            o[0] = acc[4 * r + 0] + zr[0] + ZC[r][0] + tb[0];
            o[1] = acc[4 * r + 1] + zr[1] + ZC[r][1] + tb[1];
            o[2] = acc[4 * r + 2] + zr[2] + ZC[r][2] + tb[2];
            o[3] = acc[4 * r + 3] + zr[3] + ZC[r][3] + tb[3];
            __builtin_nontemporal_store(o, (f32x4*)&orow[zq]);
        }
    }
}

extern "C" void kernel_launch(void* const* d_in, const int* in_sizes, int n_in,
                              void* d_out, int out_size, void* d_ws, size_t ws_size,
                              hipStream_t stream) {
    const int*   seq  = (const int*)d_in[0];
    const int*   cid  = (const int*)d_in[1];
    const int*   ridx = (const int*)d_in[2];
    const float* Eaa  = (const float*)d_in[3];
    const float* Epos = (const float*)d_in[4];
    const float* Ech  = (const float*)d_in[5];
    const float* Ecp  = (const float*)d_in[6];
    const float* Erp  = (const float*)d_in[7];
    const float* Wp   = (const float*)d_in[8];
    const float* bp   = (const float*)d_in[9];
    const float* lnw  = (const float*)d_in[10];
    const float* lnb  = (const float*)d_in[11];

    float* out   = (float*)d_out;
    float* s_out = out;
    float* zout  = out + L * CS;

    char* ws = (char*)d_ws;
    f16_t* u_f16 = (f16_t*)ws;                 // 256 KB
    f16_t* w3f   = (f16_t*)(ws + 262144);      // 64 KB
    float* zrow  = (float*)(ws + 327680);      // 256 KB
    float* zcol  = (float*)(ws + 589824);      // 256 KB
    float* tab   = (float*)(ws + 851968);      // 132 KB

    hipLaunchKernelGGL(k_setup, dim3(L), dim3(256), 0, stream,
                       seq, cid, ridx, Eaa, Epos, Ech, lnw, lnb, Wp, bp,
                       s_out, u_f16, zrow, zcol);
    hipLaunchKernelGGL(k_w3t, dim3(CS), dim3(CZ), 0, stream, Wp, w3f);
    hipLaunchKernelGGL(k_tab, dim3(264), dim3(CZ), 0, stream, Ecp, Erp, tab);
    hipLaunchKernelGGL(k_pair, dim3(16, 32), dim3(256), 0, stream,
                       u_f16, w3f, zrow, zcol, tab, cid, ridx, zout);
}

// Round 4
// 192.267 us; speedup vs baseline: 1.2311x; 1.2311x over previous
//
#include <hip/hip_runtime.h>
#include <hip/hip_bf16.h>

#define L 512
#define CS 256
#define CZ 128
#define LN_EPS 1e-5f

typedef _Float16 f16_t;
typedef f16_t f16x8 __attribute__((ext_vector_type(8)));
typedef float f32x4 __attribute__((ext_vector_type(4)));
typedef float f32x16 __attribute__((ext_vector_type(16)));

// ---- Kernel PREP -----------------------------------------------------------
// Per-block (i = blockIdx.x): embed + LN -> s_out, u2 (CHUNK-MAJOR f16:
// u2[c>>3][i][c&7], so k_pair can stage LDS tiles with contiguous copies),
// zrow = u@W1 + b, zcol = u@W2.
// Spare duties: blocks 0..127 build w3c (chunk-major W3^T f16), blocks
// 128..391 build tab[cp*66+rp] = Ecp[cp] + Erp[rp].
__global__ __launch_bounds__(256) void k_prep(
    const int* __restrict__ seq, const int* __restrict__ cid,
    const int* __restrict__ ridx,
    const float* __restrict__ Eaa, const float* __restrict__ Epos,
    const float* __restrict__ Ech, const float* __restrict__ lnw,
    const float* __restrict__ lnb, const float* __restrict__ Wp,
    const float* __restrict__ bp, const float* __restrict__ Ecp,
    const float* __restrict__ Erp,
    float* __restrict__ s_out, f16_t* __restrict__ u2,
    float* __restrict__ zrow, float* __restrict__ zcol,
    f16_t* __restrict__ w3c, float* __restrict__ tab)
{
    __shared__ float su[CS];
    __shared__ float red[8];
    const int i = blockIdx.x;
    const int c = threadIdx.x;

    // spare duties (independent of main work)
    if (i < 128) {
        // w3c[ch2][z][e] = W3[c = ch2*8+e][z], z = i
        w3c[(c >> 3) * (CZ * 8) + i * 8 + (c & 7)] = (f16_t)Wp[(2 * CS + c) * CZ + i];
    } else if (i < 128 + 264) {
        const int b2 = i - 128;
        if (c < CZ)
            tab[b2 * CZ + c] = Ecp[(b2 / 66) * CZ + c] + Erp[(b2 % 66) * CZ + c];
    }

    const int sq = seq[i], ri = ridx[i], ci = cid[i];
    const float v = Eaa[sq * CS + c] + Epos[ri * CS + c] + Ech[ci * CS + c];
    s_out[i * CS + c] = v;

    float s1 = v, s2 = v * v;
    #pragma unroll
    for (int o = 32; o > 0; o >>= 1) {
        s1 += __shfl_down(s1, o, 64);
        s2 += __shfl_down(s2, o, 64);
    }
    const int wv = c >> 6, lane = c & 63;
    if (lane == 0) { red[wv * 2] = s1; red[wv * 2 + 1] = s2; }
    __syncthreads();
    const float S  = red[0] + red[2] + red[4] + red[6];
    const float SS = red[1] + red[3] + red[5] + red[7];
    const float mu  = S * (1.0f / CS);
    const float var = SS * (1.0f / CS) - mu * mu;
    const float rs  = rsqrtf(var + LN_EPS);
    const float u   = (v - mu) * rs * lnw[c] + lnb[c];
    u2[(c >> 3) * (L * 8) + i * 8 + (c & 7)] = (f16_t)u;
    su[c] = u;
    __syncthreads();

    const int z = c & 127;
    const int half = c >> 7;  // 0 -> zrow(W1), 1 -> zcol(W2)
    const float* W = Wp + half * CS * CZ + z;
    float a0 = 0, a1 = 0, a2 = 0, a3 = 0;
    #pragma unroll 8
    for (int cc = 0; cc < CS; cc += 4) {
        a0 += su[cc + 0] * W[(cc + 0) * CZ];
        a1 += su[cc + 1] * W[(cc + 1) * CZ];
        a2 += su[cc + 2] * W[(cc + 2) * CZ];
        a3 += su[cc + 3] * W[(cc + 3) * CZ];
    }
    const float acc = (a0 + a1) + (a2 + a3);
    if (half) zcol[i * CZ + z] = acc;
    else      zrow[i * CZ + z] = acc + bp[z];
}

// ---- Kernel PAIR -----------------------------------------------------------
// Grid (16,64): block = 8 i x 32 j x 128 z, 4 waves = 4 z-quarters.
// u_j (16 KB) + u_i (4 KB) tiles staged in LDS chunk-major: K-loop does one
// conflict-free ds_read_b128 (uj) + 2 broadcast ds_reads (ui) per 2 MFMAs.
// A = W3^T slice persists in 64 VGPR. 2 i's in flight -> 2 independent acc
// chains. Normal stores (L2 merges the 32 partial lines per instr).
__global__ __launch_bounds__(256, 3) void k_pair(
    const f16_t* __restrict__ u2, const f16_t* __restrict__ w3c,
    const float* __restrict__ zrow, const float* __restrict__ zcol,
    const float* __restrict__ tab,
    const int* __restrict__ cid, const int* __restrict__ ridx,
    float* __restrict__ zout)
{
    __shared__ f16_t lds[(1024 + 256) * 8];  // u_j tile then u_i tile
    f16x8* lj = (f16x8*)lds;
    f16x8* li = ((f16x8*)lds) + 1024;

    const int t = threadIdx.x;
    const int lane = t & 63, wave = t >> 6;
    const int m32 = lane & 31, h = lane >> 5;
    const int j0 = blockIdx.x * 32, i0 = blockIdx.y * 8;
    const int z0 = wave * 32;

    const f16x8* pu = (const f16x8*)u2;    // [32 chunks][512 rows]
    const f16x8* pw = (const f16x8*)w3c;   // [32 chunks][128 z]

    // stage LDS tiles (contiguous src + dst)
    #pragma unroll
    for (int rep = 0; rep < 4; ++rep) {
        const int un = rep * 256 + t;            // un = ch*32 + jj
        lj[un] = pu[(un >> 5) * L + j0 + (un & 31)];
    }
    li[t] = pu[(t >> 3) * L + i0 + (t & 7)];     // t = ch*8 + ii

    // A fragments: W3T[z0+m32][(ch*2+h)*8 .. +7], coalesced, kept in regs
    f16x8 A[16];
    #pragma unroll
    for (int ch = 0; ch < 16; ++ch)
        A[ch] = pw[(ch * 2 + h) * CZ + z0 + m32];

    const int j = j0 + m32;
    const int cj = cid[j], rj = ridx[j];
    f32x4 ZC[4];
    #pragma unroll
    for (int g = 0; g < 4; ++g)
        ZC[g] = *(const f32x4*)&zcol[j * CZ + z0 + 8 * g + 4 * h];

    __syncthreads();

    #pragma unroll
    for (int ig = 0; ig < 4; ++ig) {
        f32x16 acc0 = {0,0,0,0,0,0,0,0,0,0,0,0,0,0,0,0};
        f32x16 acc1 = {0,0,0,0,0,0,0,0,0,0,0,0,0,0,0,0};
        #pragma unroll
        for (int ch = 0; ch < 16; ++ch) {
            const int cb = (ch * 2 + h);
            f16x8 uj = lj[cb * 32 + m32];        // conflict-free b128
            f16x8 u0 = li[cb * 8 + ig * 2 + 0];  // broadcast
            f16x8 u1 = li[cb * 8 + ig * 2 + 1];  // broadcast
            acc0 = __builtin_amdgcn_mfma_f32_32x32x16_f16(A[ch], u0 * uj, acc0, 0, 0, 0);
            acc1 = __builtin_amdgcn_mfma_f32_32x32x16_f16(A[ch], u1 * uj, acc1, 0, 0, 0);
        }

        #pragma unroll
        for (int t01 = 0; t01 < 2; ++t01) {
            const int i = i0 + ig * 2 + t01;
            const f32x16 acc = t01 ? acc1 : acc0;
            const int ci = cid[i], ri = ridx[i];  // wave-uniform -> scalar
            int d = ri - rj;
            d = d < -32 ? -32 : (d > 32 ? 32 : d);
            const int rp = (ci == cj) ? (d + 32) : 65;
            const int idx = (ci * 2 + cj) * 66 + rp;
            float* orow = zout + ((size_t)i * L + j) * CZ;
            #pragma unroll
            for (int g = 0; g < 4; ++g) {
                const int zq = z0 + 8 * g + 4 * h;
                f32x4 zr = *(const f32x4*)&zrow[i * CZ + zq];
                f32x4 tb = *(const f32x4*)&tab[idx * CZ + zq];
                f32x4 o;
                o[0] = acc[4 * g + 0] + zr[0] + ZC[g][0] + tb[0];
                o[1] = acc[4 * g + 1] + zr[1] + ZC[g][1] + tb[1];
                o[2] = acc[4 * g + 2] + zr[2] + ZC[g][2] + tb[2];
                o[3] = acc[4 * g + 3] + zr[3] + ZC[g][3] + tb[3];
                *(f32x4*)&orow[zq] = o;
            }
        }
    }
}

extern "C" void kernel_launch(void* const* d_in, const int* in_sizes, int n_in,
                              void* d_out, int out_size, void* d_ws, size_t ws_size,
                              hipStream_t stream) {
    const int*   seq  = (const int*)d_in[0];
    const int*   cid  = (const int*)d_in[1];
    const int*   ridx = (const int*)d_in[2];
    const float* Eaa  = (const float*)d_in[3];
    const float* Epos = (const float*)d_in[4];
    const float* Ech  = (const float*)d_in[5];
    const float* Ecp  = (const float*)d_in[6];
    const float* Erp  = (const float*)d_in[7];
    const float* Wp   = (const float*)d_in[8];
    const float* bp   = (const float*)d_in[9];
    const float* lnw  = (const float*)d_in[10];
    const float* lnb  = (const float*)d_in[11];

    float* out   = (float*)d_out;
    float* s_out = out;
    float* zout  = out + L * CS;

    char* ws = (char*)d_ws;
    f16_t* u2   = (f16_t*)ws;                 // 256 KB, chunk-major
    f16_t* w3c  = (f16_t*)(ws + 262144);      // 64 KB, chunk-major
    float* zrow = (float*)(ws + 327680);      // 256 KB
    float* zcol = (float*)(ws + 589824);      // 256 KB
    float* tab  = (float*)(ws + 851968);      // 132 KB

    hipLaunchKernelGGL(k_prep, dim3(L), dim3(256), 0, stream,
                       seq, cid, ridx, Eaa, Epos, Ech, lnw, lnb, Wp, bp,
                       Ecp, Erp, s_out, u2, zrow, zcol, w3c, tab);
    hipLaunchKernelGGL(k_pair, dim3(16, 64), dim3(256), 0, stream,
                       u2, w3c, zrow, zcol, tab, cid, ridx, zout);
}